// Round 6
// baseline (390.412 us; speedup 1.0000x reference)
//
#include <hip/hip_runtime.h>

#define T_TOK 2048
#define DIM   1024
#define FF    2048
#define NE    8
#define MAXTILES 72

typedef _Float16 f16x2 __attribute__((ext_vector_type(2)));
typedef _Float16 f16x4 __attribute__((ext_vector_type(4)));
typedef _Float16 f16x8 __attribute__((ext_vector_type(8)));
typedef float    f32x4 __attribute__((ext_vector_type(4)));

__device__ __forceinline__ f16x2 cvtpk(float a, float b) {
    return __builtin_bit_cast(f16x2, __builtin_amdgcn_cvt_pkrtz(a, b));
}
__device__ __forceinline__ int swzkey(int row) {
    return ((row ^ (row >> 3)) & 7) << 4;
}

// ---------------- router: logits/softmax/top2 + x->fp16 + fused compaction ----------------
__global__ __launch_bounds__(256) void router_kernel(
    const float* __restrict__ x,        // [T, D]
    const float* __restrict__ rw,       // [D, E]
    float* __restrict__ gates_out,      // [T, E]
    float* __restrict__ top1_out,      // [T]
    int*   __restrict__ cursor,         // [8] zeroed
    int*   __restrict__ atok,           // [E*T] segmented token lists
    int*   __restrict__ tslot,          // [2T] packed (e<<16)|i
    float* __restrict__ g1a, float* __restrict__ g2a,
    _Float16* __restrict__ xh)          // [T, D] fp16
{
    const int wid  = threadIdx.x >> 6;
    const int lane = threadIdx.x & 63;
    const int t = blockIdx.x * 4 + wid;

    float acc[NE];
#pragma unroll
    for (int e = 0; e < NE; ++e) acc[e] = 0.f;

#pragma unroll
    for (int i = 0; i < 4; ++i) {
        const int d0 = i * 256 + lane * 4;
        f32x4 xv = *(const f32x4*)&x[(size_t)t * DIM + d0];
        f16x2 h0 = cvtpk(xv[0], xv[1]);
        f16x2 h1 = cvtpk(xv[2], xv[3]);
        f16x4 hv; hv[0] = h0[0]; hv[1] = h0[1]; hv[2] = h1[0]; hv[3] = h1[1];
        *(f16x4*)&xh[(size_t)t * DIM + d0] = hv;
#pragma unroll
        for (int j = 0; j < 4; ++j) {
            f32x4 wa = *(const f32x4*)&rw[(size_t)(d0 + j) * NE];
            f32x4 wb = *(const f32x4*)&rw[(size_t)(d0 + j) * NE + 4];
            float xs = xv[j];
            acc[0] += xs * wa[0]; acc[1] += xs * wa[1];
            acc[2] += xs * wa[2]; acc[3] += xs * wa[3];
            acc[4] += xs * wb[0]; acc[5] += xs * wb[1];
            acc[6] += xs * wb[2]; acc[7] += xs * wb[3];
        }
    }
#pragma unroll
    for (int off = 32; off > 0; off >>= 1) {
#pragma unroll
        for (int e = 0; e < NE; ++e)
            acc[e] += __shfl_xor(acc[e], off, 64);
    }

    float mx = acc[0];
#pragma unroll
    for (int e = 1; e < NE; ++e) mx = fmaxf(mx, acc[e]);
    float pr[NE]; float s = 0.f;
#pragma unroll
    for (int e = 0; e < NE; ++e) { pr[e] = expf(acc[e] - mx); s += pr[e]; }

    int e1 = 0; float b1v = acc[0];
#pragma unroll
    for (int e = 1; e < NE; ++e) if (acc[e] > b1v) { b1v = acc[e]; e1 = e; }
    int e2 = (e1 == 0) ? 1 : 0; float b2v = acc[e2];
#pragma unroll
    for (int e = 0; e < NE; ++e)
        if (e != e1 && acc[e] > b2v) { b2v = acc[e]; e2 = e; }

    float p1 = pr[e1] / s, p2 = pr[e2] / s;
    float denom = fmaxf(p1 + p2, 1.1920929e-07f);
    float gg1 = p1 / denom, gg2 = p2 / denom;

    if (lane == 0) {
#pragma unroll
        for (int e = 0; e < NE; ++e)
            gates_out[(size_t)t * NE + e] = (e == e1) ? gg1 : ((e == e2) ? gg2 : 0.f);
        top1_out[t] = (float)e1;
        g1a[t] = gg1; g2a[t] = gg2;
        int i1 = atomicAdd(&cursor[e1], 1);
        atok[e1 * T_TOK + i1] = t;
        tslot[2 * t] = (e1 << 16) | i1;
        int i2 = atomicAdd(&cursor[e2], 1);
        atok[e2 * T_TOK + i2] = t;
        tslot[2 * t + 1] = (e2 << 16) | i2;
    }
}

// ---------------- unified grouped GEMM: BM=64 BN=64 BK=64, 4 waves 2x2 ----------------
// A: direct-to-register fragments (distance-1 prefetch)
// B: f32 global -> reg (distance-2 prefetch) -> cvt fp16 -> swizzled LDS dbuf
template<bool IS_FC1>
__global__ __launch_bounds__(256, 4) void fc_kernel(
    const _Float16* __restrict__ Ag,    // FC1: xh [T,D]; FC2: H [4096,FF]
    const float* __restrict__ Bg,       // FC1: w1 [E,D,F]; FC2: w2 [E,F,D]
    const float* __restrict__ bias,     // b1 [E,F] / b2 [E,D]
    const int* __restrict__ cnt,        // [8]
    const int* __restrict__ atok,       // [E*T]
    _Float16* __restrict__ Hout,        // FC1 out
    float* __restrict__ Yout)           // FC2 out
{
    constexpr int KS  = IS_FC1 ? (DIM / 64) : (FF / 64);
    constexpr int LDA = IS_FC1 ? DIM : FF;
    constexpr int LDB = IS_FC1 ? FF : DIM;

    // arithmetic tile map: blockIdx.y -> (expert e, row offset m0); base = prefix of cnt
    int e = -1, m0 = 0, base = 0, ccur = 0, accT = 0;
#pragma unroll
    for (int i = 0; i < NE; ++i) {
        int c = cnt[i];
        int nt = (c + 63) >> 6;
        if (e < 0 && (int)blockIdx.y < accT + nt) { e = i; m0 = ((int)blockIdx.y - accT) * 64; ccur = c; }
        else if (e < 0) base += c;
        accT += nt;
    }
    if (e < 0) return;
    const int n0 = blockIdx.x * 64;

    __shared__ __align__(16) _Float16 Bs[2][64 * 64];

    const int tid = threadIdx.x, wid = tid >> 6, lane = tid & 63;
    const int wr = wid >> 1, wc = wid & 1;
    const int fr = lane & 15, fq = lane >> 4;

    // per-lane A row pointers (2 rows: mi=0,1)
    const _Float16 *A0, *A1;
    {
        int r0 = m0 + wr * 32 + fr;
        int r1 = r0 + 16;
        if (r0 >= ccur) r0 = ccur - 1;
        if (r1 >= ccur) r1 = ccur - 1;
        if (IS_FC1) {
            A0 = Ag + (size_t)atok[e * T_TOK + r0] * LDA;
            A1 = Ag + (size_t)atok[e * T_TOK + r1] * LDA;
        } else {
            A0 = Ag + (size_t)(base + r0) * LDA;
            A1 = Ag + (size_t)(base + r1) * LDA;
        }
    }
    const int aoff = fq * 8;

    const int bn0 = (tid & 15) * 4, bk0 = (tid >> 4) * 4;
    const float* Bsrc = Bg + (size_t)e * DIM * FF + n0 + bn0;

    f32x4 acc[2][2];
#pragma unroll
    for (int mi = 0; mi < 2; ++mi)
#pragma unroll
        for (int ni = 0; ni < 2; ++ni) acc[mi][ni] = (f32x4)0.0f;

    f16x8 afA[2][2], afB[2][2];   // [kk][mi]
    f32x4 brA[4], brB[4];

    auto loadA = [&](f16x8 af[2][2], int kt) {
        af[0][0] = *(const f16x8*)(A0 + kt * 64 + aoff);
        af[0][1] = *(const f16x8*)(A1 + kt * 64 + aoff);
        af[1][0] = *(const f16x8*)(A0 + kt * 64 + 32 + aoff);
        af[1][1] = *(const f16x8*)(A1 + kt * 64 + 32 + aoff);
    };
    auto loadB = [&](f32x4 br[4], int kt) {
#pragma unroll
        for (int r = 0; r < 4; ++r)
            br[r] = *(const f32x4*)&Bsrc[(size_t)(kt * 64 + bk0 + r) * LDB];
    };
    auto writeB = [&](_Float16* bs, const f32x4 br[4]) {
#pragma unroll
        for (int j = 0; j < 4; ++j) {
            f16x2 p0 = cvtpk(br[0][j], br[1][j]);
            f16x2 p1 = cvtpk(br[2][j], br[3][j]);
            f16x4 hv; hv[0] = p0[0]; hv[1] = p0[1]; hv[2] = p1[0]; hv[3] = p1[1];
            int row = bn0 + j;
            *(f16x4*)((char*)bs + row * 128 + ((bk0 * 2) ^ swzkey(row))) = hv;
        }
    };
    auto mmaTile = [&](const _Float16* bs, const f16x8 af[2][2]) {
        const int r0 = wc * 32 + fr, r1 = r0 + 16;
        const int k0a = swzkey(r0), k1a = swzkey(r1);
#pragma unroll
        for (int kk = 0; kk < 2; ++kk) {
            f16x8 b0 = *(const f16x8*)((const char*)bs + r0 * 128 + ((kk * 64 + fq * 16) ^ k0a));
            f16x8 b1 = *(const f16x8*)((const char*)bs + r1 * 128 + ((kk * 64 + fq * 16) ^ k1a));
            acc[0][0] = __builtin_amdgcn_mfma_f32_16x16x32_f16(af[kk][0], b0, acc[0][0], 0, 0, 0);
            acc[0][1] = __builtin_amdgcn_mfma_f32_16x16x32_f16(af[kk][0], b1, acc[0][1], 0, 0, 0);
            acc[1][0] = __builtin_amdgcn_mfma_f32_16x16x32_f16(af[kk][1], b0, acc[1][0], 0, 0, 0);
            acc[1][1] = __builtin_amdgcn_mfma_f32_16x16x32_f16(af[kk][1], b1, acc[1][1], 0, 0, 0);
        }
    };

    // prologue: B0 -> LDS0; A0, B1 in flight
    loadB(brA, 0);
    loadA(afA, 0);
    loadB(brB, 1);
    writeB(Bs[0], brA);
    asm volatile("s_waitcnt lgkmcnt(0)" ::: "memory");
    __builtin_amdgcn_s_barrier();

    for (int k = 0; k < KS - 2; k += 2) {
        // even phase: compute tile k from Bs[0]/afA; stage B[k+1]->Bs[1]; issue A[k+1], B[k+2]
        loadA(afB, k + 1);
        loadB(brA, k + 2);
        writeB(Bs[1], brB);
        mmaTile(Bs[0], afA);
        asm volatile("s_waitcnt lgkmcnt(0)" ::: "memory");
        __builtin_amdgcn_s_barrier();
        // odd phase: compute tile k+1 from Bs[1]/afB; stage B[k+2]->Bs[0]; issue A[k+2], B[k+3]
        loadA(afA, k + 2);
        loadB(brB, k + 3);
        writeB(Bs[0], brA);
        mmaTile(Bs[1], afB);
        asm volatile("s_waitcnt lgkmcnt(0)" ::: "memory");
        __builtin_amdgcn_s_barrier();
    }
    // k = KS-2: stage B[KS-1]->Bs[1]; compute tile KS-2
    loadA(afB, KS - 1);
    writeB(Bs[1], brB);
    mmaTile(Bs[0], afA);
    asm volatile("s_waitcnt lgkmcnt(0)" ::: "memory");
    __builtin_amdgcn_s_barrier();
    // k = KS-1
    mmaTile(Bs[1], afB);

    // epilogue
    const int m_base = m0 + wr * 32 + fq * 4;
    const int n_base = n0 + wc * 32 + fr;
#pragma unroll
    for (int ni = 0; ni < 2; ++ni) {
        int n = n_base + ni * 16;
        float bv = bias[(size_t)e * LDB + n];
#pragma unroll
        for (int mi = 0; mi < 2; ++mi) {
#pragma unroll
            for (int r = 0; r < 4; ++r) {
                int m = m_base + mi * 16 + r;
                if (m < ccur) {
                    float v = acc[mi][ni][r] + bv;
                    if (IS_FC1)
                        Hout[(size_t)(base + m) * FF + n] = (_Float16)fmaxf(v, 0.f);
                    else
                        Yout[(size_t)(base + m) * DIM + n] = v;
                }
            }
        }
    }
}

// ---------------- combine: out = g1*y1 + g2*y2, where(==0, x) ----------------
__global__ __launch_bounds__(256) void combine_kernel(
    const float* __restrict__ x, const float* __restrict__ Y,
    const int* __restrict__ tslot, const float* __restrict__ g1a,
    const float* __restrict__ g2a, const int* __restrict__ cnt,
    float* __restrict__ out)
{
    __shared__ int sbase[NE];
    if (threadIdx.x == 0) {
        int s = 0;
#pragma unroll
        for (int i = 0; i < NE; ++i) { sbase[i] = s; s += cnt[i]; }
    }
    __syncthreads();
    const int t = blockIdx.x;
    const int d = threadIdx.x * 4;
    int p1 = tslot[2 * t], p2 = tslot[2 * t + 1];
    int s1 = sbase[p1 >> 16] + (p1 & 0xffff);
    int s2 = sbase[p2 >> 16] + (p2 & 0xffff);
    const float a = g1a[t], b = g2a[t];
    f32x4 y1 = *(const f32x4*)&Y[(size_t)s1 * DIM + d];
    f32x4 y2 = *(const f32x4*)&Y[(size_t)s2 * DIM + d];
    f32x4 xv = *(const f32x4*)&x[(size_t)t * DIM + d];
    f32x4 o;
#pragma unroll
    for (int j = 0; j < 4; ++j) {
        float v = a * y1[j] + b * y2[j];
        o[j] = (v == 0.f) ? xv[j] : v;
    }
    *(f32x4*)&out[(size_t)t * DIM + d] = o;
}

extern "C" void kernel_launch(void* const* d_in, const int* in_sizes, int n_in,
                              void* d_out, int out_size, void* d_ws, size_t ws_size,
                              hipStream_t stream) {
    (void)in_sizes; (void)n_in; (void)out_size; (void)ws_size;
    const float* x  = (const float*)d_in[0];
    const float* rw = (const float*)d_in[1];
    const float* w1 = (const float*)d_in[2];
    const float* b1 = (const float*)d_in[3];
    const float* w2 = (const float*)d_in[4];
    const float* b2 = (const float*)d_in[5];

    float* out       = (float*)d_out;
    float* gates_out = out + (size_t)T_TOK * DIM;
    float* top1_out  = gates_out + (size_t)T_TOK * NE;

    char* ws = (char*)d_ws;
    int*   cursor = (int*)ws;                        // [8]
    int*   atok   = (int*)(ws + 4096);               // [E*T] = 64KB
    int*   tslot  = (int*)(ws + 4096 + 65536);       // [2T]  = 16KB
    float* g1a    = (float*)(ws + 4096 + 65536 + 16384);           // 8KB
    float* g2a    = (float*)(ws + 4096 + 65536 + 16384 + 8192);    // 8KB
    _Float16* xh  = (_Float16*)(ws + 112640);                      // [T,D] fp16 = 4MB
    _Float16* H   = (_Float16*)(ws + 112640 + (size_t)4*1024*1024);    // [4096,FF] fp16 = 16MB
    float*    Y   = (float*)(ws + 112640 + (size_t)20*1024*1024);      // [4096,DIM] f32 = 16MB

    (void)hipMemsetAsync(cursor, 0, 64, stream);
    router_kernel<<<T_TOK / 4, 256, 0, stream>>>(x, rw, gates_out, top1_out, cursor,
                                                 atok, tslot, g1a, g2a, xh);
    fc_kernel<true><<<dim3(FF / 64, MAXTILES), 256, 0, stream>>>(xh, w1, b1, cursor, atok, H, Y);
    fc_kernel<false><<<dim3(DIM / 64, MAXTILES), 256, 0, stream>>>(H, w2, b2, cursor, atok, H, Y);
    combine_kernel<<<T_TOK, 256, 0, stream>>>(x, Y, tslot, g1a, g2a, cursor, out);
}

// Round 7
// 333.480 us; speedup vs baseline: 1.1707x; 1.1707x over previous
//
#include <hip/hip_runtime.h>

#define T_TOK 2048
#define DIM   1024
#define FF    2048
#define NE    8
#define MAXTILES 40

typedef _Float16 f16x2 __attribute__((ext_vector_type(2)));
typedef _Float16 f16x4 __attribute__((ext_vector_type(4)));
typedef _Float16 f16x8 __attribute__((ext_vector_type(8)));
typedef float    f32x4 __attribute__((ext_vector_type(4)));

__device__ __forceinline__ f16x2 cvtpk(float a, float b) {
    return __builtin_bit_cast(f16x2, __builtin_amdgcn_cvt_pkrtz(a, b));
}
__device__ __forceinline__ void glds16(const void* g, void* l) {
    __builtin_amdgcn_global_load_lds(
        (const __attribute__((address_space(1))) unsigned int*)g,
        (__attribute__((address_space(3))) unsigned int*)l, 16, 0, 0);
}

// ---------------- router: logits/softmax/top2 + x->fp16 + fused compaction ----------------
__global__ __launch_bounds__(256) void router_kernel(
    const float* __restrict__ x, const float* __restrict__ rw,
    float* __restrict__ gates_out, float* __restrict__ top1_out,
    int* __restrict__ cursor, int* __restrict__ atok, int* __restrict__ tslot,
    float* __restrict__ g1a, float* __restrict__ g2a,
    _Float16* __restrict__ xh)
{
    const int wid  = threadIdx.x >> 6;
    const int lane = threadIdx.x & 63;
    const int t = blockIdx.x * 4 + wid;

    float acc[NE];
#pragma unroll
    for (int e = 0; e < NE; ++e) acc[e] = 0.f;

#pragma unroll
    for (int i = 0; i < 4; ++i) {
        const int d0 = i * 256 + lane * 4;
        f32x4 xv = *(const f32x4*)&x[(size_t)t * DIM + d0];
        f16x2 h0 = cvtpk(xv[0], xv[1]);
        f16x2 h1 = cvtpk(xv[2], xv[3]);
        f16x4 hv; hv[0] = h0[0]; hv[1] = h0[1]; hv[2] = h1[0]; hv[3] = h1[1];
        *(f16x4*)&xh[(size_t)t * DIM + d0] = hv;
#pragma unroll
        for (int j = 0; j < 4; ++j) {
            f32x4 wa = *(const f32x4*)&rw[(size_t)(d0 + j) * NE];
            f32x4 wb = *(const f32x4*)&rw[(size_t)(d0 + j) * NE + 4];
            float xs = xv[j];
            acc[0] += xs * wa[0]; acc[1] += xs * wa[1];
            acc[2] += xs * wa[2]; acc[3] += xs * wa[3];
            acc[4] += xs * wb[0]; acc[5] += xs * wb[1];
            acc[6] += xs * wb[2]; acc[7] += xs * wb[3];
        }
    }
#pragma unroll
    for (int off = 32; off > 0; off >>= 1) {
#pragma unroll
        for (int e = 0; e < NE; ++e)
            acc[e] += __shfl_xor(acc[e], off, 64);
    }

    float mx = acc[0];
#pragma unroll
    for (int e = 1; e < NE; ++e) mx = fmaxf(mx, acc[e]);
    float pr[NE]; float s = 0.f;
#pragma unroll
    for (int e = 0; e < NE; ++e) { pr[e] = expf(acc[e] - mx); s += pr[e]; }

    int e1 = 0; float b1v = acc[0];
#pragma unroll
    for (int e = 1; e < NE; ++e) if (acc[e] > b1v) { b1v = acc[e]; e1 = e; }
    int e2 = (e1 == 0) ? 1 : 0; float b2v = acc[e2];
#pragma unroll
    for (int e = 0; e < NE; ++e)
        if (e != e1 && acc[e] > b2v) { b2v = acc[e]; e2 = e; }

    float p1 = pr[e1] / s, p2 = pr[e2] / s;
    float denom = fmaxf(p1 + p2, 1.1920929e-07f);
    float gg1 = p1 / denom, gg2 = p2 / denom;

    if (lane == 0) {
#pragma unroll
        for (int e = 0; e < NE; ++e)
            gates_out[(size_t)t * NE + e] = (e == e1) ? gg1 : ((e == e2) ? gg2 : 0.f);
        top1_out[t] = (float)e1;
        g1a[t] = gg1; g2a[t] = gg2;
        int i1 = atomicAdd(&cursor[e1], 1);
        atok[e1 * T_TOK + i1] = t;
        tslot[2 * t] = (e1 << 16) | i1;
        int i2 = atomicAdd(&cursor[e2], 1);
        atok[e2 * T_TOK + i2] = t;
        tslot[2 * t + 1] = (e2 << 16) | i2;
    }
}

// ---------------- weight transpose+convert: W[E][K][N] f32 -> Wt[E][N][K] fp16 ----------------
template<int K, int N>
__global__ __launch_bounds__(256) void transp_kernel(
    const float* __restrict__ W, _Float16* __restrict__ Wt)
{
    const int n0 = blockIdx.x * 64, k0 = blockIdx.y * 64, e = blockIdx.z;
    __shared__ float Ts[64][65];
    const int tid = threadIdx.x;

    const float* src = W + ((size_t)e * K + k0) * N + n0;
#pragma unroll
    for (int i = 0; i < 4; ++i) {
        int row = (tid >> 4) + i * 16;
        int col = (tid & 15) * 4;
        f32x4 v = *(const f32x4*)&src[(size_t)row * N + col];
        *(f32x4*)&Ts[row][col] = v;
    }
    __syncthreads();

    const int n = tid >> 2, c0 = (tid & 3) * 16;
    f16x8 o0, o1;
#pragma unroll
    for (int j = 0; j < 8; ++j) o0[j] = (_Float16)Ts[c0 + j][n];
#pragma unroll
    for (int j = 0; j < 8; ++j) o1[j] = (_Float16)Ts[c0 + 8 + j][n];
    _Float16* dst = Wt + ((size_t)e * N + n0 + n) * K + k0 + c0;
    *(f16x8*)dst = o0;
    *(f16x8*)(dst + 8) = o1;
}

// ---------------- fc: m97-style all-glds grouped GEMM ----------------
// BM=128 BN=64 BK=64, 4 waves (2x2, wave tile 64x32), LDS dbuf 48KB, 3 blocks/CU
template<bool IS_FC1>
__global__ __launch_bounds__(256, 3) void fc_kernel(
    const _Float16* __restrict__ Ag,    // fc1: xh [T,DIM]; fc2: H [4096,FF]
    const _Float16* __restrict__ Bt,    // fc1: w1t [E][FF][DIM]; fc2: w2t [E][DIM][FF]
    const float* __restrict__ bias,     // [E][N]
    const int* __restrict__ cnt, const int* __restrict__ atok,
    _Float16* __restrict__ Hout, _Float16* __restrict__ Yout)
{
    constexpr int K  = IS_FC1 ? DIM : FF;
    constexpr int N  = IS_FC1 ? FF : DIM;
    constexpr int KS = K / 64;

    // tile map: blockIdx.y -> (expert e, m0); base = prefix of cnt
    int e = -1, m0 = 0, base = 0, ccur = 0, accT = 0;
#pragma unroll
    for (int i = 0; i < NE; ++i) {
        int c = cnt[i];
        int nt = (c + 127) >> 7;
        if (e < 0 && (int)blockIdx.y < accT + nt) { e = i; m0 = ((int)blockIdx.y - accT) * 128; ccur = c; }
        else if (e < 0) base += c;
        accT += nt;
    }
    if (e < 0) return;
    const int n0 = blockIdx.x * 64;

    __shared__ __align__(16) _Float16 As[2][128 * 64];   // 16KB x2
    __shared__ __align__(16) _Float16 Bs[2][64 * 64];    // 8KB x2

    const int tid = threadIdx.x, wid = tid >> 6, lane = tid & 63;
    const int wr = wid >> 1, wc = wid & 1;
    const int fr = lane & 15, fq = lane >> 4;

    // A glds sources: instr i covers rows wid*32+i*8+(lane>>3), col bytes (lane&7)*16
    const char* aptr[4];
#pragma unroll
    for (int i = 0; i < 4; ++i) {
        int row = wid * 32 + i * 8 + (lane >> 3);
        int rg = m0 + row; if (rg >= ccur) rg = ccur - 1;
        size_t srow = IS_FC1 ? (size_t)atok[e * T_TOK + rg] : (size_t)(base + rg);
        aptr[i] = (const char*)(Ag + srow * K) + (lane & 7) * 16;
    }
    // B glds sources: instr j covers rows wid*16+j*8+(lane>>3)
    const char* bptr[2];
#pragma unroll
    for (int j = 0; j < 2; ++j) {
        int row = wid * 16 + j * 8 + (lane >> 3);
        bptr[j] = (const char*)(Bt + ((size_t)e * N + n0 + row) * K) + (lane & 7) * 16;
    }

    f32x4 acc[4][2];
#pragma unroll
    for (int mi = 0; mi < 4; ++mi)
#pragma unroll
        for (int ni = 0; ni < 2; ++ni) acc[mi][ni] = (f32x4)0.0f;

    auto STAGE = [&](int buf, int kt) {
        const int kb = kt * 128;
#pragma unroll
        for (int i = 0; i < 4; ++i)
            glds16(aptr[i] + kb, &As[buf][(wid * 32 + i * 8) * 64]);
#pragma unroll
        for (int j = 0; j < 2; ++j)
            glds16(bptr[j] + kb, &Bs[buf][(wid * 16 + j * 8) * 64]);
    };
    auto COMPUTE = [&](int buf) {
#pragma unroll
        for (int kk = 0; kk < 2; ++kk) {
            f16x8 af[4], bf[2];
#pragma unroll
            for (int mi = 0; mi < 4; ++mi) {
                int row = wr * 64 + mi * 16 + fr;
                af[mi] = *(const f16x8*)&As[buf][row * 64 + kk * 32 + fq * 8];
            }
#pragma unroll
            for (int ni = 0; ni < 2; ++ni) {
                int row = wc * 32 + ni * 16 + fr;
                bf[ni] = *(const f16x8*)&Bs[buf][row * 64 + kk * 32 + fq * 8];
            }
#pragma unroll
            for (int mi = 0; mi < 4; ++mi)
#pragma unroll
                for (int ni = 0; ni < 2; ++ni)
                    acc[mi][ni] = __builtin_amdgcn_mfma_f32_16x16x32_f16(af[mi], bf[ni], acc[mi][ni], 0, 0, 0);
        }
    };

    STAGE(0, 0);
    asm volatile("s_waitcnt vmcnt(0)" ::: "memory");
    __builtin_amdgcn_s_barrier();

    for (int kt = 0; kt < KS; ++kt) {
        if (kt + 1 < KS) STAGE((kt + 1) & 1, kt + 1);
        COMPUTE(kt & 1);
        asm volatile("s_waitcnt vmcnt(0)" ::: "memory");
        __builtin_amdgcn_s_barrier();
    }

    // epilogue: C row = fq*4 + r, col = fr
    const int m_base = m0 + wr * 64 + fq * 4;
    const int n_base = n0 + wc * 32 + fr;
#pragma unroll
    for (int ni = 0; ni < 2; ++ni) {
        int n = n_base + ni * 16;
        float bv = bias[(size_t)e * N + n];
#pragma unroll
        for (int mi = 0; mi < 4; ++mi) {
#pragma unroll
            for (int r = 0; r < 4; ++r) {
                int m = m_base + mi * 16 + r;
                if (m < ccur) {
                    float v = acc[mi][ni][r] + bv;
                    if (IS_FC1)
                        Hout[(size_t)(base + m) * FF + n] = (_Float16)fmaxf(v, 0.f);
                    else
                        Yout[(size_t)(base + m) * DIM + n] = (_Float16)v;
                }
            }
        }
    }
}

// ---------------- combine: out = g1*y1 + g2*y2, where(==0, x) ----------------
__global__ __launch_bounds__(256) void combine_kernel(
    const float* __restrict__ x, const _Float16* __restrict__ Y,
    const int* __restrict__ tslot, const float* __restrict__ g1a,
    const float* __restrict__ g2a, const int* __restrict__ cnt,
    float* __restrict__ out)
{
    __shared__ int sbase[NE];
    if (threadIdx.x == 0) {
        int s = 0;
#pragma unroll
        for (int i = 0; i < NE; ++i) { sbase[i] = s; s += cnt[i]; }
    }
    __syncthreads();
    const int t = blockIdx.x;
    const int d = threadIdx.x * 4;
    int p1 = tslot[2 * t], p2 = tslot[2 * t + 1];
    int s1 = sbase[p1 >> 16] + (p1 & 0xffff);
    int s2 = sbase[p2 >> 16] + (p2 & 0xffff);
    const float a = g1a[t], b = g2a[t];
    f16x4 y1 = *(const f16x4*)&Y[(size_t)s1 * DIM + d];
    f16x4 y2 = *(const f16x4*)&Y[(size_t)s2 * DIM + d];
    f32x4 xv = *(const f32x4*)&x[(size_t)t * DIM + d];
    f32x4 o;
#pragma unroll
    for (int j = 0; j < 4; ++j) {
        float v = a * (float)y1[j] + b * (float)y2[j];
        o[j] = (v == 0.f) ? xv[j] : v;
    }
    *(f32x4*)&out[(size_t)t * DIM + d] = o;
}

extern "C" void kernel_launch(void* const* d_in, const int* in_sizes, int n_in,
                              void* d_out, int out_size, void* d_ws, size_t ws_size,
                              hipStream_t stream) {
    (void)in_sizes; (void)n_in; (void)out_size; (void)ws_size;
    const float* x  = (const float*)d_in[0];
    const float* rw = (const float*)d_in[1];
    const float* w1 = (const float*)d_in[2];
    const float* b1 = (const float*)d_in[3];
    const float* w2 = (const float*)d_in[4];
    const float* b2 = (const float*)d_in[5];

    float* out       = (float*)d_out;
    float* gates_out = out + (size_t)T_TOK * DIM;
    float* top1_out  = gates_out + (size_t)T_TOK * NE;

    char* ws = (char*)d_ws;
    int*   cursor = (int*)ws;                                    // 64B
    int*   atok   = (int*)(ws + 4096);                           // 64KB
    int*   tslot  = (int*)(ws + 4096 + 65536);                   // 16KB
    float* g1a    = (float*)(ws + 4096 + 65536 + 16384);         // 8KB
    float* g2a    = (float*)(ws + 4096 + 65536 + 16384 + 8192);  // 8KB
    _Float16* xh  = (_Float16*)(ws + 112640);                                  // 4MB
    _Float16* H   = (_Float16*)(ws + 112640 + (size_t)4 * 1024 * 1024);        // 16MB
    _Float16* Yh  = (_Float16*)(ws + 112640 + (size_t)20 * 1024 * 1024);       // 8MB
    _Float16* wt  = (_Float16*)(ws + 112640 + (size_t)28 * 1024 * 1024);       // 32MB (w1t, then w2t)

    (void)hipMemsetAsync(cursor, 0, 64, stream);
    router_kernel<<<T_TOK / 4, 256, 0, stream>>>(x, rw, gates_out, top1_out, cursor,
                                                 atok, tslot, g1a, g2a, xh);
    transp_kernel<DIM, FF><<<dim3(FF / 64, DIM / 64, NE), 256, 0, stream>>>(w1, wt);
    fc_kernel<true><<<dim3(FF / 64, MAXTILES), 256, 0, stream>>>(xh, wt, b1, cursor, atok, H, Yh);
    transp_kernel<FF, DIM><<<dim3(DIM / 64, FF / 64, NE), 256, 0, stream>>>(w2, wt);
    fc_kernel<false><<<dim3(DIM / 64, MAXTILES), 256, 0, stream>>>(H, wt, b2, cursor, atok, H, Yh);
    combine_kernel<<<T_TOK, 256, 0, stream>>>(x, Yh, tslot, g1a, g2a, cursor, out);
}

// Round 8
// 287.443 us; speedup vs baseline: 1.3582x; 1.1602x over previous
//
#include <hip/hip_runtime.h>

#define T_TOK 2048
#define DIM   1024
#define FF    2048
#define NE    8
#define MAXTILES 40

typedef _Float16 f16x2 __attribute__((ext_vector_type(2)));
typedef _Float16 f16x4 __attribute__((ext_vector_type(4)));
typedef _Float16 f16x8 __attribute__((ext_vector_type(8)));
typedef float    f32x4 __attribute__((ext_vector_type(4)));

__device__ __forceinline__ f16x2 cvtpk(float a, float b) {
    return __builtin_bit_cast(f16x2, __builtin_amdgcn_cvt_pkrtz(a, b));
}
__device__ __forceinline__ void glds16(const void* g, void* l) {
    __builtin_amdgcn_global_load_lds(
        (const __attribute__((address_space(1))) unsigned int*)g,
        (__attribute__((address_space(3))) unsigned int*)l, 16, 0, 0);
}

// ---------------- router: logits/softmax/top2 + x->fp16 (NO atomics) ----------------
__global__ __launch_bounds__(256) void router_kernel(
    const float* __restrict__ x, const float* __restrict__ rw,
    float* __restrict__ gates_out, float* __restrict__ top1_out,
    int* __restrict__ e1a, int* __restrict__ e2a,
    float* __restrict__ g1a, float* __restrict__ g2a,
    _Float16* __restrict__ xh)
{
    const int wid  = threadIdx.x >> 6;
    const int lane = threadIdx.x & 63;
    const int t = blockIdx.x * 4 + wid;

    float acc[NE];
#pragma unroll
    for (int e = 0; e < NE; ++e) acc[e] = 0.f;

#pragma unroll
    for (int i = 0; i < 4; ++i) {
        const int d0 = i * 256 + lane * 4;
        f32x4 xv = *(const f32x4*)&x[(size_t)t * DIM + d0];
        f16x2 h0 = cvtpk(xv[0], xv[1]);
        f16x2 h1 = cvtpk(xv[2], xv[3]);
        f16x4 hv; hv[0] = h0[0]; hv[1] = h0[1]; hv[2] = h1[0]; hv[3] = h1[1];
        *(f16x4*)&xh[(size_t)t * DIM + d0] = hv;
#pragma unroll
        for (int j = 0; j < 4; ++j) {
            f32x4 wa = *(const f32x4*)&rw[(size_t)(d0 + j) * NE];
            f32x4 wb = *(const f32x4*)&rw[(size_t)(d0 + j) * NE + 4];
            float xs = xv[j];
            acc[0] += xs * wa[0]; acc[1] += xs * wa[1];
            acc[2] += xs * wa[2]; acc[3] += xs * wa[3];
            acc[4] += xs * wb[0]; acc[5] += xs * wb[1];
            acc[6] += xs * wb[2]; acc[7] += xs * wb[3];
        }
    }
#pragma unroll
    for (int off = 32; off > 0; off >>= 1) {
#pragma unroll
        for (int e = 0; e < NE; ++e)
            acc[e] += __shfl_xor(acc[e], off, 64);
    }

    float mx = acc[0];
#pragma unroll
    for (int e = 1; e < NE; ++e) mx = fmaxf(mx, acc[e]);
    float pr[NE]; float s = 0.f;
#pragma unroll
    for (int e = 0; e < NE; ++e) { pr[e] = expf(acc[e] - mx); s += pr[e]; }

    int e1 = 0; float b1v = acc[0];
#pragma unroll
    for (int e = 1; e < NE; ++e) if (acc[e] > b1v) { b1v = acc[e]; e1 = e; }
    int e2 = (e1 == 0) ? 1 : 0; float b2v = acc[e2];
#pragma unroll
    for (int e = 0; e < NE; ++e)
        if (e != e1 && acc[e] > b2v) { b2v = acc[e]; e2 = e; }

    float p1 = pr[e1] / s, p2 = pr[e2] / s;
    float denom = fmaxf(p1 + p2, 1.1920929e-07f);
    float gg1 = p1 / denom, gg2 = p2 / denom;

    // parallel scalar writes across lanes (no atomics)
    if (lane < 8) gates_out[(size_t)t * NE + lane] = (lane == e1) ? gg1 : ((lane == e2) ? gg2 : 0.f);
    if (lane == 8)  top1_out[t] = (float)e1;
    if (lane == 9)  g1a[t] = gg1;
    if (lane == 10) g2a[t] = gg2;
    if (lane == 11) e1a[t] = e1;
    if (lane == 12) e2a[t] = e2;
}

// ---------------- compact: single block, ballot-based, no global atomics ----------------
__global__ __launch_bounds__(1024) void compact_kernel(
    const int* __restrict__ e1a, const int* __restrict__ e2a,
    int* __restrict__ cursor, int* __restrict__ atok, int* __restrict__ tslot)
{
    __shared__ int lbase[NE];
    __shared__ int woff[16][NE];
    const int tid = threadIdx.x, w = tid >> 6, lane = tid & 63;
    if (tid < NE) lbase[tid] = 0;
    __syncthreads();

    for (int b = 0; b < 4; ++b) {
        const int k = b * 1024 + tid;
        const int t = k >> 1;
        const int ex = (k & 1) ? e2a[t] : e1a[t];

        unsigned long long mymask = 0;
#pragma unroll
        for (int e = 0; e < NE; ++e) {
            unsigned long long m = __ballot(ex == e);
            if (ex == e) mymask = m;
            if (lane == e) woff[w][e] = __popcll(m);
        }
        const int rank = __popcll(mymask & ((1ull << lane) - 1));
        __syncthreads();

        if (tid < NE) {   // exclusive prefix across 16 waves for expert tid
            int s2 = lbase[tid];
            for (int ww = 0; ww < 16; ++ww) { int c = woff[ww][tid]; woff[ww][tid] = s2; s2 += c; }
            lbase[tid] = s2;
        }
        __syncthreads();

        const int slot = woff[w][ex] + rank;
        atok[ex * T_TOK + slot] = t;
        tslot[k] = (ex << 16) | slot;
        __syncthreads();
    }
    if (tid < NE) cursor[tid] = lbase[tid];
}

// ---------------- weight transpose+convert: W[E][K][N] f32 -> Wt[E][N][K] fp16 ----------------
template<int K, int N>
__global__ __launch_bounds__(256) void transp_kernel(
    const float* __restrict__ W, _Float16* __restrict__ Wt)
{
    const int n0 = blockIdx.x * 64, k0 = blockIdx.y * 64, e = blockIdx.z;
    __shared__ float Ts[64][65];
    const int tid = threadIdx.x;

    const float* src = W + ((size_t)e * K + k0) * N + n0;
#pragma unroll
    for (int i = 0; i < 4; ++i) {
        int row = (tid >> 4) + i * 16;
        int col = (tid & 15) * 4;
        f32x4 v = *(const f32x4*)&src[(size_t)row * N + col];
        *(f32x4*)&Ts[row][col] = v;
    }
    __syncthreads();

    const int n = tid >> 2, c0 = (tid & 3) * 16;
    f16x8 o0, o1;
#pragma unroll
    for (int j = 0; j < 8; ++j) o0[j] = (_Float16)Ts[c0 + j][n];
#pragma unroll
    for (int j = 0; j < 8; ++j) o1[j] = (_Float16)Ts[c0 + 8 + j][n];
    _Float16* dst = Wt + ((size_t)e * N + n0 + n) * K + k0 + c0;
    *(f16x8*)dst = o0;
    *(f16x8*)(dst + 8) = o1;
}

// ---------------- fc: all-glds grouped GEMM, counted-vmcnt pipeline ----------------
// BM=128 BN=64 BK=64, 4 waves (2x2, wave tile 64x32), LDS dbuf 48KB, 3 blocks/CU
template<bool IS_FC1>
__global__ __launch_bounds__(256, 3) void fc_kernel(
    const _Float16* __restrict__ Ag,    // fc1: xh [T,DIM]; fc2: H [4096,FF]
    const _Float16* __restrict__ Bt,    // fc1: w1t [E][FF][DIM]; fc2: w2t [E][DIM][FF]
    const float* __restrict__ bias,     // [E][N]
    const int* __restrict__ cnt, const int* __restrict__ atok,
    _Float16* __restrict__ Hout, _Float16* __restrict__ Yout)
{
    constexpr int K  = IS_FC1 ? DIM : FF;
    constexpr int N  = IS_FC1 ? FF : DIM;
    constexpr int KS = K / 64;

    int e = -1, m0 = 0, base = 0, ccur = 0, accT = 0;
#pragma unroll
    for (int i = 0; i < NE; ++i) {
        int c = cnt[i];
        int nt = (c + 127) >> 7;
        if (e < 0 && (int)blockIdx.y < accT + nt) { e = i; m0 = ((int)blockIdx.y - accT) * 128; ccur = c; }
        else if (e < 0) base += c;
        accT += nt;
    }
    if (e < 0) return;
    const int n0 = blockIdx.x * 64;

    __shared__ __align__(16) _Float16 As[2][128 * 64];
    __shared__ __align__(16) _Float16 Bs[2][64 * 64];

    const int tid = threadIdx.x, wid = tid >> 6, lane = tid & 63;
    const int wr = wid >> 1, wc = wid & 1;
    const int fr = lane & 15, fq = lane >> 4;

    const char* aptr[4];
#pragma unroll
    for (int i = 0; i < 4; ++i) {
        int row = wid * 32 + i * 8 + (lane >> 3);
        int rg = m0 + row; if (rg >= ccur) rg = ccur - 1;
        size_t srow = IS_FC1 ? (size_t)atok[e * T_TOK + rg] : (size_t)(base + rg);
        aptr[i] = (const char*)(Ag + srow * K) + (lane & 7) * 16;
    }
    const char* bptr[2];
#pragma unroll
    for (int j = 0; j < 2; ++j) {
        int row = wid * 16 + j * 8 + (lane >> 3);
        bptr[j] = (const char*)(Bt + ((size_t)e * N + n0 + row) * K) + (lane & 7) * 16;
    }

    f32x4 acc[4][2];
#pragma unroll
    for (int mi = 0; mi < 4; ++mi)
#pragma unroll
        for (int ni = 0; ni < 2; ++ni) acc[mi][ni] = (f32x4)0.0f;

    auto STAGE = [&](int buf, int kt) {
        const int kb = kt * 128;
#pragma unroll
        for (int i = 0; i < 4; ++i)
            glds16(aptr[i] + kb, &As[buf][(wid * 32 + i * 8) * 64]);
#pragma unroll
        for (int j = 0; j < 2; ++j)
            glds16(bptr[j] + kb, &Bs[buf][(wid * 16 + j * 8) * 64]);
    };
    auto COMPUTE = [&](int buf) {
#pragma unroll
        for (int kk = 0; kk < 2; ++kk) {
            f16x8 af[4], bf[2];
#pragma unroll
            for (int mi = 0; mi < 4; ++mi) {
                int row = wr * 64 + mi * 16 + fr;
                af[mi] = *(const f16x8*)&As[buf][row * 64 + kk * 32 + fq * 8];
            }
#pragma unroll
            for (int ni = 0; ni < 2; ++ni) {
                int row = wc * 32 + ni * 16 + fr;
                bf[ni] = *(const f16x8*)&Bs[buf][row * 64 + kk * 32 + fq * 8];
            }
#pragma unroll
            for (int mi = 0; mi < 4; ++mi)
#pragma unroll
                for (int ni = 0; ni < 2; ++ni)
                    acc[mi][ni] = __builtin_amdgcn_mfma_f32_16x16x32_f16(af[mi], bf[ni], acc[mi][ni], 0, 0, 0);
        }
    };

    STAGE(0, 0);

    for (int kt = 0; kt < KS; ++kt) {
        if (kt + 1 < KS) {
            STAGE((kt + 1) & 1, kt + 1);
            asm volatile("s_waitcnt vmcnt(6)" ::: "memory");   // stage(kt) landed; stage(kt+1) in flight
        } else {
            asm volatile("s_waitcnt vmcnt(0)" ::: "memory");
        }
        __builtin_amdgcn_s_barrier();
        COMPUTE(kt & 1);
        asm volatile("s_waitcnt lgkmcnt(0)" ::: "memory");
        __builtin_amdgcn_s_barrier();
    }

    const int m_base = m0 + wr * 64 + fq * 4;
    const int n_base = n0 + wc * 32 + fr;
#pragma unroll
    for (int ni = 0; ni < 2; ++ni) {
        int n = n_base + ni * 16;
        float bv = bias[(size_t)e * N + n];
#pragma unroll
        for (int mi = 0; mi < 4; ++mi) {
#pragma unroll
            for (int r = 0; r < 4; ++r) {
                int m = m_base + mi * 16 + r;
                if (m < ccur) {
                    float v = acc[mi][ni][r] + bv;
                    if (IS_FC1)
                        Hout[(size_t)(base + m) * FF + n] = (_Float16)fmaxf(v, 0.f);
                    else
                        Yout[(size_t)(base + m) * DIM + n] = (_Float16)v;
                }
            }
        }
    }
}

// ---------------- combine: out = g1*y1 + g2*y2, where(==0, x) ----------------
__global__ __launch_bounds__(256) void combine_kernel(
    const float* __restrict__ x, const _Float16* __restrict__ Y,
    const int* __restrict__ tslot, const float* __restrict__ g1a,
    const float* __restrict__ g2a, const int* __restrict__ cnt,
    float* __restrict__ out)
{
    __shared__ int sbase[NE];
    if (threadIdx.x == 0) {
        int s = 0;
#pragma unroll
        for (int i = 0; i < NE; ++i) { sbase[i] = s; s += cnt[i]; }
    }
    __syncthreads();
    const int t = blockIdx.x;
    const int d = threadIdx.x * 4;
    int p1 = tslot[2 * t], p2 = tslot[2 * t + 1];
    int s1 = sbase[p1 >> 16] + (p1 & 0xffff);
    int s2 = sbase[p2 >> 16] + (p2 & 0xffff);
    const float a = g1a[t], b = g2a[t];
    f16x4 y1 = *(const f16x4*)&Y[(size_t)s1 * DIM + d];
    f16x4 y2 = *(const f16x4*)&Y[(size_t)s2 * DIM + d];
    f32x4 xv = *(const f32x4*)&x[(size_t)t * DIM + d];
    f32x4 o;
#pragma unroll
    for (int j = 0; j < 4; ++j) {
        float v = a * (float)y1[j] + b * (float)y2[j];
        o[j] = (v == 0.f) ? xv[j] : v;
    }
    *(f32x4*)&out[(size_t)t * DIM + d] = o;
}

extern "C" void kernel_launch(void* const* d_in, const int* in_sizes, int n_in,
                              void* d_out, int out_size, void* d_ws, size_t ws_size,
                              hipStream_t stream) {
    (void)in_sizes; (void)n_in; (void)out_size; (void)ws_size;
    const float* x  = (const float*)d_in[0];
    const float* rw = (const float*)d_in[1];
    const float* w1 = (const float*)d_in[2];
    const float* b1 = (const float*)d_in[3];
    const float* w2 = (const float*)d_in[4];
    const float* b2 = (const float*)d_in[5];

    float* out       = (float*)d_out;
    float* gates_out = out + (size_t)T_TOK * DIM;
    float* top1_out  = gates_out + (size_t)T_TOK * NE;

    char* ws = (char*)d_ws;
    int*   cursor = (int*)ws;                        // 32B (written by compact)
    int*   atok   = (int*)(ws + 4096);               // 64KB
    int*   tslot  = (int*)(ws + 69632);              // 16KB
    float* g1a    = (float*)(ws + 86016);            // 8KB
    float* g2a    = (float*)(ws + 94208);            // 8KB
    int*   e1a    = (int*)(ws + 102400);             // 8KB
    int*   e2a    = (int*)(ws + 110592);             // 8KB
    _Float16* xh  = (_Float16*)(ws + 131072);                               // 4MB
    _Float16* H   = (_Float16*)(ws + 131072 + (size_t)4 * 1024 * 1024);     // 16MB
    _Float16* Yh  = (_Float16*)(ws + 131072 + (size_t)20 * 1024 * 1024);    // 8MB
    _Float16* wt  = (_Float16*)(ws + 131072 + (size_t)28 * 1024 * 1024);    // 32MB (w1t, then w2t)

    router_kernel<<<T_TOK / 4, 256, 0, stream>>>(x, rw, gates_out, top1_out,
                                                 e1a, e2a, g1a, g2a, xh);
    transp_kernel<DIM, FF><<<dim3(FF / 64, DIM / 64, NE), 256, 0, stream>>>(w1, wt);
    compact_kernel<<<1, 1024, 0, stream>>>(e1a, e2a, cursor, atok, tslot);
    fc_kernel<true><<<dim3(FF / 64, MAXTILES), 256, 0, stream>>>(xh, wt, b1, cursor, atok, H, Yh);
    transp_kernel<FF, DIM><<<dim3(DIM / 64, FF / 64, NE), 256, 0, stream>>>(w2, wt);
    fc_kernel<false><<<dim3(DIM / 64, MAXTILES), 256, 0, stream>>>(H, wt, b2, cursor, atok, H, Yh);
    combine_kernel<<<T_TOK, 256, 0, stream>>>(x, Yh, tslot, g1a, g2a, cursor, out);
}

// Round 9
// 262.419 us; speedup vs baseline: 1.4877x; 1.0954x over previous
//
#include <hip/hip_runtime.h>

#define T_TOK 2048
#define DIM   1024
#define FF    2048
#define NE    8
#define MAXTILES 40

typedef _Float16 f16x2 __attribute__((ext_vector_type(2)));
typedef _Float16 f16x4 __attribute__((ext_vector_type(4)));
typedef _Float16 f16x8 __attribute__((ext_vector_type(8)));
typedef float    f32x4 __attribute__((ext_vector_type(4)));

__device__ __forceinline__ f16x2 cvtpk(float a, float b) {
    return __builtin_bit_cast(f16x2, __builtin_amdgcn_cvt_pkrtz(a, b));
}
__device__ __forceinline__ void glds16(const void* g, void* l) {
    __builtin_amdgcn_global_load_lds(
        (const __attribute__((address_space(1))) unsigned int*)g,
        (__attribute__((address_space(3))) unsigned int*)l, 16, 0, 0);
}

// ---------------- router: logits/softmax/top2 + x->fp16 (NO atomics) ----------------
__global__ __launch_bounds__(256) void router_kernel(
    const float* __restrict__ x, const float* __restrict__ rw,
    float* __restrict__ gates_out, float* __restrict__ top1_out,
    int* __restrict__ e1a, int* __restrict__ e2a,
    float* __restrict__ g1a, float* __restrict__ g2a,
    _Float16* __restrict__ xh)
{
    const int wid  = threadIdx.x >> 6;
    const int lane = threadIdx.x & 63;
    const int t = blockIdx.x * 4 + wid;

    float acc[NE];
#pragma unroll
    for (int e = 0; e < NE; ++e) acc[e] = 0.f;

#pragma unroll
    for (int i = 0; i < 4; ++i) {
        const int d0 = i * 256 + lane * 4;
        f32x4 xv = *(const f32x4*)&x[(size_t)t * DIM + d0];
        f16x2 h0 = cvtpk(xv[0], xv[1]);
        f16x2 h1 = cvtpk(xv[2], xv[3]);
        f16x4 hv; hv[0] = h0[0]; hv[1] = h0[1]; hv[2] = h1[0]; hv[3] = h1[1];
        *(f16x4*)&xh[(size_t)t * DIM + d0] = hv;
#pragma unroll
        for (int j = 0; j < 4; ++j) {
            f32x4 wa = *(const f32x4*)&rw[(size_t)(d0 + j) * NE];
            f32x4 wb = *(const f32x4*)&rw[(size_t)(d0 + j) * NE + 4];
            float xs = xv[j];
            acc[0] += xs * wa[0]; acc[1] += xs * wa[1];
            acc[2] += xs * wa[2]; acc[3] += xs * wa[3];
            acc[4] += xs * wb[0]; acc[5] += xs * wb[1];
            acc[6] += xs * wb[2]; acc[7] += xs * wb[3];
        }
    }
#pragma unroll
    for (int off = 32; off > 0; off >>= 1) {
#pragma unroll
        for (int e = 0; e < NE; ++e)
            acc[e] += __shfl_xor(acc[e], off, 64);
    }

    float mx = acc[0];
#pragma unroll
    for (int e = 1; e < NE; ++e) mx = fmaxf(mx, acc[e]);
    float pr[NE]; float s = 0.f;
#pragma unroll
    for (int e = 0; e < NE; ++e) { pr[e] = expf(acc[e] - mx); s += pr[e]; }

    int e1 = 0; float b1v = acc[0];
#pragma unroll
    for (int e = 1; e < NE; ++e) if (acc[e] > b1v) { b1v = acc[e]; e1 = e; }
    int e2 = (e1 == 0) ? 1 : 0; float b2v = acc[e2];
#pragma unroll
    for (int e = 0; e < NE; ++e)
        if (e != e1 && acc[e] > b2v) { b2v = acc[e]; e2 = e; }

    float p1 = pr[e1] / s, p2 = pr[e2] / s;
    float denom = fmaxf(p1 + p2, 1.1920929e-07f);
    float gg1 = p1 / denom, gg2 = p2 / denom;

    if (lane < 8) gates_out[(size_t)t * NE + lane] = (lane == e1) ? gg1 : ((lane == e2) ? gg2 : 0.f);
    if (lane == 8)  top1_out[t] = (float)e1;
    if (lane == 9)  g1a[t] = gg1;
    if (lane == 10) g2a[t] = gg2;
    if (lane == 11) e1a[t] = e1;
    if (lane == 12) e2a[t] = e2;
}

// ---------------- compact: single block, ballot-based, no global atomics ----------------
__global__ __launch_bounds__(1024) void compact_kernel(
    const int* __restrict__ e1a, const int* __restrict__ e2a,
    int* __restrict__ cursor, int* __restrict__ atok, int* __restrict__ tslot)
{
    __shared__ int lbase[NE];
    __shared__ int woff[16][NE];
    const int tid = threadIdx.x, w = tid >> 6, lane = tid & 63;
    if (tid < NE) lbase[tid] = 0;
    __syncthreads();

    for (int b = 0; b < 4; ++b) {
        const int k = b * 1024 + tid;
        const int t = k >> 1;
        const int ex = (k & 1) ? e2a[t] : e1a[t];

        unsigned long long mymask = 0;
#pragma unroll
        for (int e = 0; e < NE; ++e) {
            unsigned long long m = __ballot(ex == e);
            if (ex == e) mymask = m;
            if (lane == e) woff[w][e] = __popcll(m);
        }
        const int rank = __popcll(mymask & ((1ull << lane) - 1));
        __syncthreads();

        if (tid < NE) {
            int s2 = lbase[tid];
            for (int ww = 0; ww < 16; ++ww) { int c = woff[ww][tid]; woff[ww][tid] = s2; s2 += c; }
            lbase[tid] = s2;
        }
        __syncthreads();

        const int slot = woff[w][ex] + rank;
        atok[ex * T_TOK + slot] = t;
        tslot[k] = (ex << 16) | slot;
        __syncthreads();
    }
    if (tid < NE) cursor[tid] = lbase[tid];
}

// ---------------- weight transpose+convert: W[E][K][N] f32 -> Wt[E][N][K] fp16 ----------------
template<int K, int N>
__global__ __launch_bounds__(256) void transp_kernel(
    const float* __restrict__ W, _Float16* __restrict__ Wt)
{
    const int n0 = blockIdx.x * 64, k0 = blockIdx.y * 64, e = blockIdx.z;
    __shared__ float Ts[64][65];
    const int tid = threadIdx.x;

    const float* src = W + ((size_t)e * K + k0) * N + n0;
#pragma unroll
    for (int i = 0; i < 4; ++i) {
        int row = (tid >> 4) + i * 16;
        int col = (tid & 15) * 4;
        f32x4 v = *(const f32x4*)&src[(size_t)row * N + col];
        *(f32x4*)&Ts[row][col] = v;
    }
    __syncthreads();

    const int n = tid >> 2, c0 = (tid & 3) * 16;
    f16x8 o0, o1;
#pragma unroll
    for (int j = 0; j < 8; ++j) o0[j] = (_Float16)Ts[c0 + j][n];
#pragma unroll
    for (int j = 0; j < 8; ++j) o1[j] = (_Float16)Ts[c0 + 8 + j][n];
    _Float16* dst = Wt + ((size_t)e * N + n0 + n) * K + k0 + c0;
    *(f16x8*)dst = o0;
    *(f16x8*)(dst + 8) = o1;
}

// ---------------- fc: all-glds grouped GEMM, counted-vmcnt + T2 swizzle ----------------
// BM=128 BN=64 BK=64, 4 waves (2x2, wave tile 64x32), LDS dbuf 48KB, 3 blocks/CU
// Swizzle (rule 21): glds dest linear; SOURCE col-slot = (lane&7)^(lane>>3);
// reads XOR slot with (row&7). 16B slots -> 2 lanes/bank (free).
template<bool IS_FC1>
__global__ __launch_bounds__(256, 3) void fc_kernel(
    const _Float16* __restrict__ Ag,
    const _Float16* __restrict__ Bt,
    const float* __restrict__ bias,
    const int* __restrict__ cnt, const int* __restrict__ atok,
    _Float16* __restrict__ Hout, _Float16* __restrict__ Yout)
{
    constexpr int K  = IS_FC1 ? DIM : FF;
    constexpr int N  = IS_FC1 ? FF : DIM;
    constexpr int KS = K / 64;

    int e = -1, m0 = 0, base = 0, ccur = 0, accT = 0;
#pragma unroll
    for (int i = 0; i < NE; ++i) {
        int c = cnt[i];
        int nt = (c + 127) >> 7;
        if (e < 0 && (int)blockIdx.y < accT + nt) { e = i; m0 = ((int)blockIdx.y - accT) * 128; ccur = c; }
        else if (e < 0) base += c;
        accT += nt;
    }
    if (e < 0) return;
    const int n0 = blockIdx.x * 64;

    __shared__ __align__(16) _Float16 As[2][128 * 64];
    __shared__ __align__(16) _Float16 Bs[2][64 * 64];

    const int tid = threadIdx.x, wid = tid >> 6, lane = tid & 63;
    const int wr = wid >> 1, wc = wid & 1;
    const int fr = lane & 15, fq = lane >> 4;

    // pre-swizzled source col slot (16B units) within each 128B k-row
    const int scol = ((lane & 7) ^ (lane >> 3)) * 16;

    const char* aptr[4];
#pragma unroll
    for (int i = 0; i < 4; ++i) {
        int row = wid * 32 + i * 8 + (lane >> 3);
        int rg = m0 + row; if (rg >= ccur) rg = ccur - 1;
        size_t srow = IS_FC1 ? (size_t)atok[e * T_TOK + rg] : (size_t)(base + rg);
        aptr[i] = (const char*)(Ag + srow * K) + scol;
    }
    const char* bptr[2];
#pragma unroll
    for (int j = 0; j < 2; ++j) {
        int row = wid * 16 + j * 8 + (lane >> 3);
        bptr[j] = (const char*)(Bt + ((size_t)e * N + n0 + row) * K) + scol;
    }

    f32x4 acc[4][2];
#pragma unroll
    for (int mi = 0; mi < 4; ++mi)
#pragma unroll
        for (int ni = 0; ni < 2; ++ni) acc[mi][ni] = (f32x4)0.0f;

    auto STAGE = [&](int buf, int kt) {
        const int kb = kt * 128;
#pragma unroll
        for (int i = 0; i < 4; ++i)
            glds16(aptr[i] + kb, &As[buf][(wid * 32 + i * 8) * 64]);
#pragma unroll
        for (int j = 0; j < 2; ++j)
            glds16(bptr[j] + kb, &Bs[buf][(wid * 16 + j * 8) * 64]);
    };
    auto COMPUTE = [&](int buf) {
#pragma unroll
        for (int kk = 0; kk < 2; ++kk) {
            f16x8 af[4], bf[2];
#pragma unroll
            for (int mi = 0; mi < 4; ++mi) {
                int row = wr * 64 + mi * 16 + fr;
                int slot = (kk * 4 + fq) ^ (fr & 7);
                af[mi] = *(const f16x8*)&As[buf][row * 64 + slot * 8];
            }
#pragma unroll
            for (int ni = 0; ni < 2; ++ni) {
                int row = wc * 32 + ni * 16 + fr;
                int slot = (kk * 4 + fq) ^ (fr & 7);
                bf[ni] = *(const f16x8*)&Bs[buf][row * 64 + slot * 8];
            }
#pragma unroll
            for (int mi = 0; mi < 4; ++mi)
#pragma unroll
                for (int ni = 0; ni < 2; ++ni)
                    acc[mi][ni] = __builtin_amdgcn_mfma_f32_16x16x32_f16(af[mi], bf[ni], acc[mi][ni], 0, 0, 0);
        }
    };

    STAGE(0, 0);

    for (int kt = 0; kt < KS; ++kt) {
        if (kt + 1 < KS) {
            STAGE((kt + 1) & 1, kt + 1);
            asm volatile("s_waitcnt vmcnt(6)" ::: "memory");
        } else {
            asm volatile("s_waitcnt vmcnt(0)" ::: "memory");
        }
        __builtin_amdgcn_s_barrier();
        COMPUTE(kt & 1);
        asm volatile("s_waitcnt lgkmcnt(0)" ::: "memory");
        __builtin_amdgcn_s_barrier();
    }

    const int m_base = m0 + wr * 64 + fq * 4;
    const int n_base = n0 + wc * 32 + fr;
#pragma unroll
    for (int ni = 0; ni < 2; ++ni) {
        int n = n_base + ni * 16;
        float bv = bias[(size_t)e * N + n];
#pragma unroll
        for (int mi = 0; mi < 4; ++mi) {
#pragma unroll
            for (int r = 0; r < 4; ++r) {
                int m = m_base + mi * 16 + r;
                if (m < ccur) {
                    float v = acc[mi][ni][r] + bv;
                    if (IS_FC1)
                        Hout[(size_t)(base + m) * FF + n] = (_Float16)fmaxf(v, 0.f);
                    else
                        Yout[(size_t)(base + m) * DIM + n] = (_Float16)v;
                }
            }
        }
    }
}

// ---------------- combine: out = g1*y1 + g2*y2, where(==0, x) ----------------
__global__ __launch_bounds__(256) void combine_kernel(
    const float* __restrict__ x, const _Float16* __restrict__ Y,
    const int* __restrict__ tslot, const float* __restrict__ g1a,
    const float* __restrict__ g2a, const int* __restrict__ cnt,
    float* __restrict__ out)
{
    __shared__ int sbase[NE];
    if (threadIdx.x == 0) {
        int s = 0;
#pragma unroll
        for (int i = 0; i < NE; ++i) { sbase[i] = s; s += cnt[i]; }
    }
    __syncthreads();
    const int t = blockIdx.x;
    const int d = threadIdx.x * 4;
    int p1 = tslot[2 * t], p2 = tslot[2 * t + 1];
    int s1 = sbase[p1 >> 16] + (p1 & 0xffff);
    int s2 = sbase[p2 >> 16] + (p2 & 0xffff);
    const float a = g1a[t], b = g2a[t];
    f16x4 y1 = *(const f16x4*)&Y[(size_t)s1 * DIM + d];
    f16x4 y2 = *(const f16x4*)&Y[(size_t)s2 * DIM + d];
    f32x4 xv = *(const f32x4*)&x[(size_t)t * DIM + d];
    f32x4 o;
#pragma unroll
    for (int j = 0; j < 4; ++j) {
        float v = a * (float)y1[j] + b * (float)y2[j];
        o[j] = (v == 0.f) ? xv[j] : v;
    }
    *(f32x4*)&out[(size_t)t * DIM + d] = o;
}

extern "C" void kernel_launch(void* const* d_in, const int* in_sizes, int n_in,
                              void* d_out, int out_size, void* d_ws, size_t ws_size,
                              hipStream_t stream) {
    (void)in_sizes; (void)n_in; (void)out_size; (void)ws_size;
    const float* x  = (const float*)d_in[0];
    const float* rw = (const float*)d_in[1];
    const float* w1 = (const float*)d_in[2];
    const float* b1 = (const float*)d_in[3];
    const float* w2 = (const float*)d_in[4];
    const float* b2 = (const float*)d_in[5];

    float* out       = (float*)d_out;
    float* gates_out = out + (size_t)T_TOK * DIM;
    float* top1_out  = gates_out + (size_t)T_TOK * NE;

    char* ws = (char*)d_ws;
    int*   cursor = (int*)ws;
    int*   atok   = (int*)(ws + 4096);
    int*   tslot  = (int*)(ws + 69632);
    float* g1a    = (float*)(ws + 86016);
    float* g2a    = (float*)(ws + 94208);
    int*   e1a    = (int*)(ws + 102400);
    int*   e2a    = (int*)(ws + 110592);
    _Float16* xh  = (_Float16*)(ws + 131072);                               // 4MB
    _Float16* H   = (_Float16*)(ws + 131072 + (size_t)4 * 1024 * 1024);     // 16MB
    _Float16* Yh  = (_Float16*)(ws + 131072 + (size_t)20 * 1024 * 1024);    // 8MB
    _Float16* wt  = (_Float16*)(ws + 131072 + (size_t)28 * 1024 * 1024);    // 32MB (w1t, then w2t)

    router_kernel<<<T_TOK / 4, 256, 0, stream>>>(x, rw, gates_out, top1_out,
                                                 e1a, e2a, g1a, g2a, xh);
    transp_kernel<DIM, FF><<<dim3(FF / 64, DIM / 64, NE), 256, 0, stream>>>(w1, wt);
    compact_kernel<<<1, 1024, 0, stream>>>(e1a, e2a, cursor, atok, tslot);
    fc_kernel<true><<<dim3(FF / 64, MAXTILES), 256, 0, stream>>>(xh, wt, b1, cursor, atok, H, Yh);
    transp_kernel<FF, DIM><<<dim3(DIM / 64, FF / 64, NE), 256, 0, stream>>>(w2, wt);
    fc_kernel<false><<<dim3(DIM / 64, MAXTILES), 256, 0, stream>>>(H, wt, b2, cursor, atok, H, Yh);
    combine_kernel<<<T_TOK, 256, 0, stream>>>(x, Yh, tslot, g1a, g2a, cursor, out);
}